// Round 1
// baseline (610.913 us; speedup 1.0000x reference)
//
#include <hip/hip_runtime.h>
#include <hip/hip_bf16.h>
#include <math.h>

// Problem constants (S,B,L,E) = (4,4,4096,1024), H=8, D=128
#define SS 4
#define BB 4
#define LL 4096
#define EE 1024
#define HH 8
#define DD 128
#define TT (BB*LL)              // 16384 tokens
#define AGG_ELEMS ((long)TT*EE) // 16,777,216 floats of `aggregated`

using bf16  = __hip_bfloat16;
using bfp2  = __hip_bfloat162;
using bhalf8_t  = __attribute__((ext_vector_type(8))) short;  // 8 bf16 (4 VGPRs)
using floatx4_t = __attribute__((ext_vector_type(4))) float;  // MFMA acc

__device__ __forceinline__ void gload16(const void* g, void* l) {
  // async global->LDS, 16B/lane; LDS dest is wave-uniform base + lane*16
  __builtin_amdgcn_global_load_lds((const __attribute__((address_space(1))) void*)g,
                                   (__attribute__((address_space(3))) void*)l, 16, 0, 0);
}

// ---- K0: cast Wv, Wout (f32, ExE each) to bf16 -------------------------------
__global__ __launch_bounds__(256) void k_convert(const float* __restrict__ Wv,
                                                 const float* __restrict__ Wo,
                                                 bf16* __restrict__ WvB,
                                                 bf16* __restrict__ WoB) {
  int i = blockIdx.x * 256 + threadIdx.x;   // 0..(E*E/4)-1, 4 elems each
  float4 a = ((const float4*)Wv)[i];
  float4 b = ((const float4*)Wo)[i];
  bfp2 p;
  p.x = __float2bfloat16(a.x); p.y = __float2bfloat16(a.y); ((bfp2*)WvB)[2*i]   = p;
  p.x = __float2bfloat16(a.z); p.y = __float2bfloat16(a.w); ((bfp2*)WvB)[2*i+1] = p;
  p.x = __float2bfloat16(b.x); p.y = __float2bfloat16(b.y); ((bfp2*)WoB)[2*i]   = p;
  p.x = __float2bfloat16(b.z); p.y = __float2bfloat16(b.w); ((bfp2*)WoB)[2*i+1] = p;
}

// ---- K1: q[f] = query . Wq[f,:] + bq[f]   (one wave per f) -------------------
__global__ __launch_bounds__(256) void k_q(const float* __restrict__ query,
                                           const float* __restrict__ Wq,
                                           const float* __restrict__ bq,
                                           float* __restrict__ q) {
  int lane = threadIdx.x & 63;
  int f = blockIdx.x * 4 + (threadIdx.x >> 6);
  const float* wr = Wq + (long)f * EE;
  float acc = 0.f;
  for (int e = lane; e < EE; e += 64) acc += query[e] * wr[e];
#pragma unroll
  for (int o = 32; o; o >>= 1) acc += __shfl_down(acc, o);
  if (!lane) q[f] = acc + bq[f];
}

// ---- K2: qk[h,e] = scale * sum_d q[h,d] * Wk[h*D+d, e] -----------------------
__global__ __launch_bounds__(256) void k_qk(const float* __restrict__ q,
                                            const float* __restrict__ Wk,
                                            float* __restrict__ qk) {
  int idx = blockIdx.x * 256 + threadIdx.x;  // 0..8191
  int h = idx >> 10, e = idx & 1023;
  const float* qh = q + h * DD;
  float acc = 0.f;
  for (int d = 0; d < DD; ++d) acc += qh[d] * Wk[(long)(h * DD + d) * EE + e];
  qk[idx] = acc * 0.088388347648318447f;  // 1/sqrt(128); bk dropped (softmax-invariant)
}

// ---- K3: fused logits+softmax+weights + y (attn-weighted x), bf16 y out ------
// Block: 256 threads = 4 waves, one wave per token; x for 4 tokens in LDS (64KB)
__global__ __launch_bounds__(256) void k_attn_y(const float* __restrict__ X,
                                                const float* __restrict__ qk,
                                                float* __restrict__ attn_ws,
                                                float* __restrict__ wout,
                                                bf16* __restrict__ y,
                                                int h0, int hc, int doAttn) {
  __shared__ float xs[16][EE];  // [tok_local*4 + s][e], 64 KB
  int tid = threadIdx.x;
  long tok0 = (long)blockIdx.x * 4;
#pragma unroll
  for (int it = 0; it < 16; ++it) {
    int j = it * 256 + tid;
    int row = j >> 8, c4 = j & 255;
    long tok = tok0 + (row >> 2);
    int s = row & 3;
    const float4* src = (const float4*)(X + ((long)s * TT + tok) * EE) + c4;
    *(float4*)&xs[row][c4 * 4] = *src;
  }
  __syncthreads();

  int wave = tid >> 6, lane = tid & 63;
  long tok = tok0 + wave;
  int r0 = wave * 4;
  float attn[HH][SS];

  if (doAttn) {
    float acc[HH][SS];
#pragma unroll
    for (int h = 0; h < HH; ++h)
#pragma unroll
      for (int s = 0; s < SS; ++s) acc[h][s] = 0.f;
    for (int i = 0; i < 16; ++i) {
      int e = i * 64 + lane;
      float xv[SS];
#pragma unroll
      for (int s = 0; s < SS; ++s) xv[s] = xs[r0 + s][e];
#pragma unroll
      for (int h = 0; h < HH; ++h) {
        float qv = qk[h * EE + e];
#pragma unroll
        for (int s = 0; s < SS; ++s) acc[h][s] += qv * xv[s];
      }
    }
#pragma unroll
    for (int h = 0; h < HH; ++h)
#pragma unroll
      for (int s = 0; s < SS; ++s)
#pragma unroll
        for (int o = 1; o < 64; o <<= 1) acc[h][s] += __shfl_xor(acc[h][s], o);
#pragma unroll
    for (int h = 0; h < HH; ++h) {
      float m = fmaxf(fmaxf(acc[h][0], acc[h][1]), fmaxf(acc[h][2], acc[h][3]));
      float p0 = __expf(acc[h][0] - m), p1 = __expf(acc[h][1] - m);
      float p2 = __expf(acc[h][2] - m), p3 = __expf(acc[h][3] - m);
      float inv = 1.f / (p0 + p1 + p2 + p3);
      attn[h][0] = p0 * inv; attn[h][1] = p1 * inv;
      attn[h][2] = p2 * inv; attn[h][3] = p3 * inv;
    }
    if (lane == 0) {
#pragma unroll
      for (int h = 0; h < HH; ++h)
#pragma unroll
        for (int s = 0; s < SS; ++s) attn_ws[tok * 32 + h * 4 + s] = attn[h][s];
#pragma unroll
      for (int s = 0; s < SS; ++s) {
        float wsum = 0.125f * (attn[0][s] + attn[1][s] + attn[2][s] + attn[3][s] +
                               attn[4][s] + attn[5][s] + attn[6][s] + attn[7][s]);
        wout[(long)s * TT + tok] = wsum;  // weights[s,b,l]
      }
    }
  } else {
#pragma unroll
    for (int h = 0; h < HH; ++h)
#pragma unroll
      for (int s = 0; s < SS; ++s) attn[h][s] = attn_ws[tok * 32 + h * 4 + s];
  }

  // y[t,h,e] = sum_s attn[h][s] * x[s,e], bf16, layout [h-h0][t][e]
#pragma unroll
  for (int h = 0; h < HH; ++h) {
    if (h < h0 || h >= h0 + hc) continue;  // uniform
    float a0 = attn[h][0], a1 = attn[h][1], a2 = attn[h][2], a3 = attn[h][3];
    bf16* yr = y + ((long)(h - h0) * TT + tok) * EE;
#pragma unroll
    for (int i = 0; i < 8; ++i) {
      int e = i * 128 + lane * 2;
      float2 v0 = *(const float2*)&xs[r0][e];
      float2 v1 = *(const float2*)&xs[r0 + 1][e];
      float2 v2 = *(const float2*)&xs[r0 + 2][e];
      float2 v3 = *(const float2*)&xs[r0 + 3][e];
      float u0 = a0 * v0.x + a1 * v1.x + a2 * v2.x + a3 * v3.x;
      float u1 = a0 * v0.y + a1 * v1.y + a2 * v2.y + a3 * v3.y;
      bfp2 pk; pk.x = __float2bfloat16(u0); pk.y = __float2bfloat16(u1);
      *(bfp2*)&yr[e] = pk;
    }
  }
}

// ---- K4/K5: m97-style 128x128 bf16 MFMA GEMM, C = A * Bt^T + bias ------------
// A: MxK row-major bf16 (M via blockIdx.x*128). Bt: NxK row-major bf16.
// blockIdx.y shifts A by aStrideY, Bt by btStrideY, columns by 128.
template <bool OUTF32>
__global__ __launch_bounds__(256) void k_gemm128(const bf16* __restrict__ A,
                                                 const bf16* __restrict__ Bt,
                                                 const float* __restrict__ bias,
                                                 void* __restrict__ C,
                                                 int K, int ldc, int nbase0,
                                                 long aStrideY, long btStrideY) {
  __shared__ bf16 As[128 * 64];  // [m][k], 16 KB
  __shared__ bf16 Bs[128 * 64];  // [n][k], 16 KB
  A  += (long)blockIdx.y * aStrideY;
  Bt += (long)blockIdx.y * btStrideY;
  int tid = threadIdx.x, wave = tid >> 6, lane = tid & 63;
  long m0 = (long)blockIdx.x * 128;
  int wm = wave >> 1, wn = wave & 1;  // 2x2 wave quadrants of 64x64
  floatx4_t acc[4][4];
#pragma unroll
  for (int i = 0; i < 4; ++i)
#pragma unroll
    for (int j = 0; j < 4; ++j) acc[i][j] = (floatx4_t){0.f, 0.f, 0.f, 0.f};

  int lrow = lane >> 3;        // 0..7 within 8-row segment
  int lcol = (lane & 7) * 8;   // bf16 col offset (16B per lane)

  for (int k0 = 0; k0 < K; k0 += 64) {
#pragma unroll
    for (int i = 0; i < 4; ++i) {
      int seg = wave * 4 + i;            // 16 segs x 1024B = 16KB tile
      int row = seg * 8 + lrow;
      gload16(A  + (m0 + row) * (long)K + k0 + lcol, &As[seg * 512]);
      gload16(Bt + (long)row * K        + k0 + lcol, &Bs[seg * 512]);
    }
    __syncthreads();  // compiler drains vmcnt before s_barrier
#pragma unroll
    for (int kk = 0; kk < 2; ++kk) {
      bhalf8_t af[4], bfr[4];
#pragma unroll
      for (int mi = 0; mi < 4; ++mi) {
        int m = wm * 64 + mi * 16 + (lane & 15);
        af[mi] = *(const bhalf8_t*)&As[m * 64 + kk * 32 + (lane >> 4) * 8];
      }
#pragma unroll
      for (int ni = 0; ni < 4; ++ni) {
        int n = wn * 64 + ni * 16 + (lane & 15);
        bfr[ni] = *(const bhalf8_t*)&Bs[n * 64 + kk * 32 + (lane >> 4) * 8];
      }
#pragma unroll
      for (int mi = 0; mi < 4; ++mi)
#pragma unroll
        for (int ni = 0; ni < 4; ++ni)
          acc[mi][ni] = __builtin_amdgcn_mfma_f32_16x16x32_bf16(af[mi], bfr[ni], acc[mi][ni], 0, 0, 0);
    }
    __syncthreads();
  }

  // epilogue: D row = (lane>>4)*4 + r, col = lane&15  [m89-verified layout]
  int cl = lane & 15, rg = (lane >> 4) * 4;
#pragma unroll
  for (int mi = 0; mi < 4; ++mi) {
    long trow = m0 + wm * 64 + mi * 16 + rg;
#pragma unroll
    for (int ni = 0; ni < 4; ++ni) {
      int n = nbase0 + blockIdx.y * 128 + wn * 64 + ni * 16 + cl;
      float bv = bias[n];
#pragma unroll
      for (int r = 0; r < 4; ++r) {
        float v = acc[mi][ni][r] + bv;
        if (OUTF32) ((float*)C)[(trow + r) * (long)ldc + n] = v;
        else        ((bf16*)C)[(trow + r) * (long)ldc + n] = __float2bfloat16(v);
      }
    }
  }
}

extern "C" void kernel_launch(void* const* d_in, const int* in_sizes, int n_in,
                              void* d_out, int out_size, void* d_ws, size_t ws_size,
                              hipStream_t stream) {
  const float* SO  = (const float*)d_in[0];  // (S,B,L,E)
  const float* SQ  = (const float*)d_in[1];  // (1,1,E)
  const float* IPW = (const float*)d_in[2];  // (3E,E)
  const float* IPB = (const float*)d_in[3];  // (3E,)
  const float* OPW = (const float*)d_in[4];  // (E,E)
  const float* OPB = (const float*)d_in[5];  // (E,)
  float* out = (float*)d_out;                // aggregated (B,L,E) then weights (S,B,L)
  char* ws = (char*)d_ws;

  size_t off = 0;
  auto alloc = [&](size_t bytes) -> void* {
    void* p = ws + off;
    off = (off + bytes + 255) & ~(size_t)255;
    return p;
  };
  float* q    = (float*)alloc((size_t)EE * 4);
  float* qk   = (float*)alloc((size_t)HH * EE * 4);
  float* attn = (float*)alloc((size_t)TT * 32 * 4);      // 2 MB
  bf16*  WvB  = (bf16*) alloc((size_t)EE * EE * 2);      // 2 MB
  bf16*  WoB  = (bf16*) alloc((size_t)EE * EE * 2);      // 2 MB
  bf16*  ctxB = (bf16*) alloc((size_t)TT * EE * 2);      // 32 MB
  int HC = HH;
  while (HC > 1 && off + (size_t)TT * HC * EE * 2 > ws_size) HC >>= 1;
  bf16* y = (bf16*)(ws + off);                           // HC * 32 MB

  k_convert<<<EE * EE / 1024, 256, 0, stream>>>(IPW + 2 * EE * EE, OPW, WvB, WoB);
  k_q<<<EE / 4, 256, 0, stream>>>(SQ, IPW, IPB, q);
  k_qk<<<HH * EE / 256, 256, 0, stream>>>(q, IPW + EE * EE, qk);

  for (int h0 = 0; h0 < HH; h0 += HC) {
    k_attn_y<<<TT / 4, 256, 0, stream>>>(SO, qk, attn, out + AGG_ELEMS, y, h0, HC, h0 == 0 ? 1 : 0);
    // ctx[:, h*128:(h+1)*128] = y_h @ Wv_h^T + bv   (bf16 out)
    k_gemm128<false><<<dim3(TT / 128, HC), 256, 0, stream>>>(
        y, WvB + (long)h0 * DD * EE, IPB + 2 * EE, ctxB,
        EE, EE, h0 * DD, (long)TT * EE, (long)DD * EE);
  }
  // aggregated = ctx @ Wout^T + bout   (f32 out)
  k_gemm128<true><<<dim3(TT / 128, HH), 256, 0, stream>>>(
      ctxB, WoB, OPB, out, EE, EE, 0, 0L, (long)DD * EE);
}